// Round 1
// baseline (375.785 us; speedup 1.0000x reference)
//
#include <hip/hip_runtime.h>
#include <math.h>

// Problem constants (from reference): B=4096 segments, D=256 features, O=4 outputs.
#define BDIM 256   // 4 waves of 64

// ---------------------------------------------------------------------------
// Kernel 1: exclusive prefix sum of segment counts -> offsets (single block).
// B=4096, trivial cost (~16 KB read/write).
// ---------------------------------------------------------------------------
__global__ void seg_offsets_kernel(const int* __restrict__ counts,
                                   int* __restrict__ offsets, int B) {
  __shared__ int partial[BDIM];
  const int tid = threadIdx.x;
  const int chunk = (B + BDIM - 1) / BDIM;   // 16 for B=4096
  const int base = tid * chunk;

  int s = 0;
  for (int i = 0; i < chunk; ++i) {
    const int idx = base + i;
    if (idx < B) s += counts[idx];
  }
  partial[tid] = s;
  __syncthreads();

  // Hillis-Steele inclusive scan over the 256 per-thread partials.
  for (int off = 1; off < BDIM; off <<= 1) {
    int v = (tid >= off) ? partial[tid - off] : 0;
    __syncthreads();
    partial[tid] += v;
    __syncthreads();
  }

  int run = (tid == 0) ? 0 : partial[tid - 1];  // exclusive base for this chunk
  for (int i = 0; i < chunk; ++i) {
    const int idx = base + i;
    if (idx < B) {
      offsets[idx] = run;
      run += counts[idx];
    }
  }
}

// ---------------------------------------------------------------------------
// Kernel 2: fused segment-mean + projection + sigmoid.
// One block per segment; 4 waves, each wave streams whole node rows
// (64 lanes x float4 = 256 floats = one row), projecting through W on the fly.
// ---------------------------------------------------------------------------
__global__ __launch_bounds__(BDIM) void mean_proj_kernel(
    const float* __restrict__ x, const int* __restrict__ counts,
    const int* __restrict__ offsets, const float* __restrict__ W,
    const float* __restrict__ b, float* __restrict__ out) {
  const int seg  = blockIdx.x;
  const int tid  = threadIdx.x;
  const int lane = tid & 63;
  const int wave = tid >> 6;            // 0..3

  const int cnt   = counts[seg];
  const long start = (long)offsets[seg];

  // Each lane owns features [4*lane, 4*lane+4). W is [4][256] row-major.
  const float4* W4 = (const float4*)W;
  const float4 w0 = W4[0 * 64 + lane];
  const float4 w1 = W4[1 * 64 + lane];
  const float4 w2 = W4[2 * 64 + lane];
  const float4 w3 = W4[3 * 64 + lane];

  float a0 = 0.f, a1 = 0.f, a2 = 0.f, a3 = 0.f;

  // Wave w handles nodes w, w+4, w+8, ... of this segment.
  for (int n = wave; n < cnt; n += 4) {
    const float4* row = (const float4*)(x + (start + n) * 256L);
    const float4 xv = row[lane];        // coalesced: 64 lanes x 16 B = full row
    a0 += xv.x * w0.x + xv.y * w0.y + xv.z * w0.z + xv.w * w0.w;
    a1 += xv.x * w1.x + xv.y * w1.y + xv.z * w1.z + xv.w * w1.w;
    a2 += xv.x * w2.x + xv.y * w2.y + xv.z * w2.z + xv.w * w2.w;
    a3 += xv.x * w3.x + xv.y * w3.y + xv.z * w3.z + xv.w * w3.w;
  }

  // Wave-level butterfly reduction (64 lanes).
  for (int off = 32; off > 0; off >>= 1) {
    a0 += __shfl_down(a0, off, 64);
    a1 += __shfl_down(a1, off, 64);
    a2 += __shfl_down(a2, off, 64);
    a3 += __shfl_down(a3, off, 64);
  }

  __shared__ float red[4][4];           // [wave][o]
  if (lane == 0) {
    red[wave][0] = a0;
    red[wave][1] = a1;
    red[wave][2] = a2;
    red[wave][3] = a3;
  }
  __syncthreads();

  if (tid < 4) {                        // thread o handles output o
    const int o = tid;
    const float s = red[0][o] + red[1][o] + red[2][o] + red[3][o];
    const float v = s / (float)cnt + b[o];
    out[seg * 4 + o] = 1.0f / (1.0f + expf(-v));
  }
}

// ---------------------------------------------------------------------------
extern "C" void kernel_launch(void* const* d_in, const int* in_sizes, int n_in,
                              void* d_out, int out_size, void* d_ws, size_t ws_size,
                              hipStream_t stream) {
  const float* x        = (const float*)d_in[0];
  const int*   node_num = (const int*)d_in[1];   // int32 on device (JAX default)
  const float* W        = (const float*)d_in[2];
  const float* b        = (const float*)d_in[3];
  float*       out      = (float*)d_out;

  const int B = in_sizes[1];                     // 4096 segments
  int* offsets = (int*)d_ws;                     // 16 KB scratch

  seg_offsets_kernel<<<1, BDIM, 0, stream>>>(node_num, offsets, B);
  mean_proj_kernel<<<B, BDIM, 0, stream>>>(x, node_num, offsets, W, b, out);
}

// Round 2
// 372.221 us; speedup vs baseline: 1.0096x; 1.0096x over previous
//
#include <hip/hip_runtime.h>
#include <math.h>

// Problem constants (from reference): B=4096 segments, D=256 features, O=4 outputs.
#define BDIM 256   // 4 waves of 64

// ---------------------------------------------------------------------------
// Kernel 1: exclusive prefix sum of segment counts -> offsets (single block).
// B=4096, trivial cost (~16 KB read/write, ~5 us).
// ---------------------------------------------------------------------------
__global__ void seg_offsets_kernel(const int* __restrict__ counts,
                                   int* __restrict__ offsets, int B) {
  __shared__ int partial[BDIM];
  const int tid = threadIdx.x;
  const int chunk = (B + BDIM - 1) / BDIM;   // 16 for B=4096
  const int base = tid * chunk;

  int s = 0;
  for (int i = 0; i < chunk; ++i) {
    const int idx = base + i;
    if (idx < B) s += counts[idx];
  }
  partial[tid] = s;
  __syncthreads();

  // Hillis-Steele inclusive scan over the 256 per-thread partials.
  for (int off = 1; off < BDIM; off <<= 1) {
    int v = (tid >= off) ? partial[tid - off] : 0;
    __syncthreads();
    partial[tid] += v;
    __syncthreads();
  }

  int run = (tid == 0) ? 0 : partial[tid - 1];  // exclusive base for this chunk
  for (int i = 0; i < chunk; ++i) {
    const int idx = base + i;
    if (idx < B) {
      offsets[idx] = run;
      run += counts[idx];
    }
  }
}

// ---------------------------------------------------------------------------
// Kernel 2: fused segment-mean + projection + sigmoid.
// One block per segment; 4 waves. Wave w owns row groups [w*4+j + 16k], j<4:
// each main-loop iteration issues 4 INDEPENDENT dwordx4 loads (4 rows) before
// any FMA consumes them -> 4+ outstanding loads/wave for latency hiding.
// All branches on n are wave-uniform (n depends only on wave id + loop).
// ---------------------------------------------------------------------------
__global__ __launch_bounds__(BDIM) void mean_proj_kernel(
    const float* __restrict__ x, const int* __restrict__ counts,
    const int* __restrict__ offsets, const float* __restrict__ W,
    const float* __restrict__ b, float* __restrict__ out) {
  const int seg  = blockIdx.x;
  const int tid  = threadIdx.x;
  const int lane = tid & 63;
  const int wave = tid >> 6;            // 0..3

  const int  cnt   = counts[seg];
  const long start = (long)offsets[seg];

  // Each lane owns features [4*lane, 4*lane+4). W is [4][256] row-major.
  const float4* W4 = (const float4*)W;
  const float4 w0 = W4[0 * 64 + lane];
  const float4 w1 = W4[1 * 64 + lane];
  const float4 w2 = W4[2 * 64 + lane];
  const float4 w3 = W4[3 * 64 + lane];

  float a0 = 0.f, a1 = 0.f, a2 = 0.f, a3 = 0.f;

  // Row r (256 floats) = 64 float4; lane's slice at xb[r*64].
  const float4* xb = (const float4*)x + start * 64 + lane;

  int n = wave * 4;
  // Main loop: 4 rows per wave-iteration, 16 rows per block sweep.
  for (; n + 3 < cnt; n += 16) {
    const float4 v0 = xb[(long)(n + 0) * 64];
    const float4 v1 = xb[(long)(n + 1) * 64];
    const float4 v2 = xb[(long)(n + 2) * 64];
    const float4 v3 = xb[(long)(n + 3) * 64];

    a0 += v0.x * w0.x + v0.y * w0.y + v0.z * w0.z + v0.w * w0.w;
    a1 += v0.x * w1.x + v0.y * w1.y + v0.z * w1.z + v0.w * w1.w;
    a2 += v0.x * w2.x + v0.y * w2.y + v0.z * w2.z + v0.w * w2.w;
    a3 += v0.x * w3.x + v0.y * w3.y + v0.z * w3.z + v0.w * w3.w;

    a0 += v1.x * w0.x + v1.y * w0.y + v1.z * w0.z + v1.w * w0.w;
    a1 += v1.x * w1.x + v1.y * w1.y + v1.z * w1.z + v1.w * w1.w;
    a2 += v1.x * w2.x + v1.y * w2.y + v1.z * w2.z + v1.w * w2.w;
    a3 += v1.x * w3.x + v1.y * w3.y + v1.z * w3.z + v1.w * w3.w;

    a0 += v2.x * w0.x + v2.y * w0.y + v2.z * w0.z + v2.w * w0.w;
    a1 += v2.x * w1.x + v2.y * w1.y + v2.z * w1.z + v2.w * w1.w;
    a2 += v2.x * w2.x + v2.y * w2.y + v2.z * w2.z + v2.w * w2.w;
    a3 += v2.x * w3.x + v2.y * w3.y + v2.z * w3.z + v2.w * w3.w;

    a0 += v3.x * w0.x + v3.y * w0.y + v3.z * w0.z + v3.w * w0.w;
    a1 += v3.x * w1.x + v3.y * w1.y + v3.z * w1.z + v3.w * w1.w;
    a2 += v3.x * w2.x + v3.y * w2.y + v3.z * w2.z + v3.w * w2.w;
    a3 += v3.x * w3.x + v3.y * w3.y + v3.z * w3.z + v3.w * w3.w;
  }
  // Tail: <=3 rows of this wave's last group (wave-uniform trip count).
  for (; n < cnt; ++n) {
    const float4 v = xb[(long)n * 64];
    a0 += v.x * w0.x + v.y * w0.y + v.z * w0.z + v.w * w0.w;
    a1 += v.x * w1.x + v.y * w1.y + v.z * w1.z + v.w * w1.w;
    a2 += v.x * w2.x + v.y * w2.y + v.z * w2.z + v.w * w2.w;
    a3 += v.x * w3.x + v.y * w3.y + v.z * w3.z + v.w * w3.w;
  }

  // Wave-level butterfly reduction (64 lanes).
  for (int off = 32; off > 0; off >>= 1) {
    a0 += __shfl_down(a0, off, 64);
    a1 += __shfl_down(a1, off, 64);
    a2 += __shfl_down(a2, off, 64);
    a3 += __shfl_down(a3, off, 64);
  }

  __shared__ float red[4][4];           // [wave][o]
  if (lane == 0) {
    red[wave][0] = a0;
    red[wave][1] = a1;
    red[wave][2] = a2;
    red[wave][3] = a3;
  }
  __syncthreads();

  if (tid < 4) {                        // thread o handles output o
    const int o = tid;
    const float s = red[0][o] + red[1][o] + red[2][o] + red[3][o];
    const float v = s / (float)cnt + b[o];
    out[seg * 4 + o] = 1.0f / (1.0f + expf(-v));
  }
}

// ---------------------------------------------------------------------------
extern "C" void kernel_launch(void* const* d_in, const int* in_sizes, int n_in,
                              void* d_out, int out_size, void* d_ws, size_t ws_size,
                              hipStream_t stream) {
  const float* x        = (const float*)d_in[0];
  const int*   node_num = (const int*)d_in[1];   // int32 on device (JAX default)
  const float* W        = (const float*)d_in[2];
  const float* b        = (const float*)d_in[3];
  float*       out      = (float*)d_out;

  const int B = in_sizes[1];                     // 4096 segments
  int* offsets = (int*)d_ws;                     // 16 KB scratch

  seg_offsets_kernel<<<1, BDIM, 0, stream>>>(node_num, offsets, B);
  mean_proj_kernel<<<B, BDIM, 0, stream>>>(x, node_num, offsets, W, b, out);
}

// Round 3
// 344.234 us; speedup vs baseline: 1.0917x; 1.0813x over previous
//
#include <hip/hip_runtime.h>
#include <math.h>

// Problem constants (from reference): B=4096 segments, D=256 features, O=4 outputs.
#define BDIM 256   // 4 waves of 64

typedef float v4f __attribute__((ext_vector_type(4)));

// ---------------------------------------------------------------------------
// Kernel 1: exclusive prefix sum of segment counts -> offsets (single block).
// B=4096, trivial cost (~16 KB read/write, ~5 us).
// ---------------------------------------------------------------------------
__global__ void seg_offsets_kernel(const int* __restrict__ counts,
                                   int* __restrict__ offsets, int B) {
  __shared__ int partial[BDIM];
  const int tid = threadIdx.x;
  const int chunk = (B + BDIM - 1) / BDIM;   // 16 for B=4096
  const int base = tid * chunk;

  int s = 0;
  for (int i = 0; i < chunk; ++i) {
    const int idx = base + i;
    if (idx < B) s += counts[idx];
  }
  partial[tid] = s;
  __syncthreads();

  // Hillis-Steele inclusive scan over the 256 per-thread partials.
  for (int off = 1; off < BDIM; off <<= 1) {
    int v = (tid >= off) ? partial[tid - off] : 0;
    __syncthreads();
    partial[tid] += v;
    __syncthreads();
  }

  int run = (tid == 0) ? 0 : partial[tid - 1];  // exclusive base for this chunk
  for (int i = 0; i < chunk; ++i) {
    const int idx = base + i;
    if (idx < B) {
      offsets[idx] = run;
      run += counts[idx];
    }
  }
}

// ---------------------------------------------------------------------------
// Kernel 2: fused segment-mean + projection + sigmoid.
// One block per segment; 4 waves. Wave w owns row groups {w*4+j+16k, j<4}.
// Software-pipelined: next group's 4 nontemporal dwordx4 loads issue before
// the current group's 64 FMAs -> up to 8 outstanding 1KB wave-loads.
// Stepping pointer p advances 16 KB/iter; the 4 loads use immediate byte
// offsets 0/1024/2048/3072 (no per-load 64-bit mul).
// Accumulation order identical to the R1/R2 kernel (absmax was 0.0).
// ---------------------------------------------------------------------------
__global__ __launch_bounds__(BDIM) void mean_proj_kernel(
    const float* __restrict__ x, const int* __restrict__ counts,
    const int* __restrict__ offsets, const float* __restrict__ W,
    const float* __restrict__ b, float* __restrict__ out) {
  const int seg  = blockIdx.x;
  const int tid  = threadIdx.x;
  const int lane = tid & 63;
  const int wave = tid >> 6;            // 0..3

  const int  cnt   = counts[seg];
  const long start = (long)offsets[seg];

  // Each lane owns features [4*lane, 4*lane+4). W is [4][256] row-major.
  const v4f* W4 = (const v4f*)W;
  const v4f w0 = W4[0 * 64 + lane];
  const v4f w1 = W4[1 * 64 + lane];
  const v4f w2 = W4[2 * 64 + lane];
  const v4f w3 = W4[3 * 64 + lane];

  float a0 = 0.f, a1 = 0.f, a2 = 0.f, a3 = 0.f;

  // Row r (256 floats) = 64 v4f; lane's slice at xb[r*64].
  const v4f* xb = (const v4f*)x + start * 64 + lane;

  int n = wave * 4;
  const v4f* p = xb + (long)n * 64;

  v4f v0, v1, v2, v3;
  bool have = (n + 3 < cnt);            // wave-uniform
  if (have) {
    v0 = __builtin_nontemporal_load(p + 0);
    v1 = __builtin_nontemporal_load(p + 64);
    v2 = __builtin_nontemporal_load(p + 128);
    v3 = __builtin_nontemporal_load(p + 192);
  }
  while (have) {
    const int nn = n + 16;
    const bool next = (nn + 3 < cnt);   // wave-uniform
    const v4f* q = p + 1024;            // +16 rows = 16 KB
    v4f u0, u1, u2, u3;
    if (next) {                         // prefetch next group before FMAs
      u0 = __builtin_nontemporal_load(q + 0);
      u1 = __builtin_nontemporal_load(q + 64);
      u2 = __builtin_nontemporal_load(q + 128);
      u3 = __builtin_nontemporal_load(q + 192);
    }

    a0 += v0.x * w0.x + v0.y * w0.y + v0.z * w0.z + v0.w * w0.w;
    a1 += v0.x * w1.x + v0.y * w1.y + v0.z * w1.z + v0.w * w1.w;
    a2 += v0.x * w2.x + v0.y * w2.y + v0.z * w2.z + v0.w * w2.w;
    a3 += v0.x * w3.x + v0.y * w3.y + v0.z * w3.z + v0.w * w3.w;

    a0 += v1.x * w0.x + v1.y * w0.y + v1.z * w0.z + v1.w * w0.w;
    a1 += v1.x * w1.x + v1.y * w1.y + v1.z * w1.z + v1.w * w1.w;
    a2 += v1.x * w2.x + v1.y * w2.y + v1.z * w2.z + v1.w * w2.w;
    a3 += v1.x * w3.x + v1.y * w3.y + v1.z * w3.z + v1.w * w3.w;

    a0 += v2.x * w0.x + v2.y * w0.y + v2.z * w0.z + v2.w * w0.w;
    a1 += v2.x * w1.x + v2.y * w1.y + v2.z * w1.z + v2.w * w1.w;
    a2 += v2.x * w2.x + v2.y * w2.y + v2.z * w2.z + v2.w * w2.w;
    a3 += v2.x * w3.x + v2.y * w3.y + v2.z * w3.z + v2.w * w3.w;

    a0 += v3.x * w0.x + v3.y * w0.y + v3.z * w0.z + v3.w * w0.w;
    a1 += v3.x * w1.x + v3.y * w1.y + v3.z * w1.z + v3.w * w1.w;
    a2 += v3.x * w2.x + v3.y * w2.y + v3.z * w2.z + v3.w * w2.w;
    a3 += v3.x * w3.x + v3.y * w3.y + v3.z * w3.z + v3.w * w3.w;

    if (next) { v0 = u0; v1 = u1; v2 = u2; v3 = u3; }
    p = q; n = nn; have = next;
  }
  // Tail: <=3 rows, belongs to exactly one wave (others fall out of range).
  for (; n < cnt; ++n) {
    const v4f v = __builtin_nontemporal_load(xb + (long)n * 64);
    a0 += v.x * w0.x + v.y * w0.y + v.z * w0.z + v.w * w0.w;
    a1 += v.x * w1.x + v.y * w1.y + v.z * w1.z + v.w * w1.w;
    a2 += v.x * w2.x + v.y * w2.y + v.z * w2.z + v.w * w2.w;
    a3 += v.x * w3.x + v.y * w3.y + v.z * w3.z + v.w * w3.w;
  }

  // Wave-level butterfly reduction (64 lanes).
  for (int off = 32; off > 0; off >>= 1) {
    a0 += __shfl_down(a0, off, 64);
    a1 += __shfl_down(a1, off, 64);
    a2 += __shfl_down(a2, off, 64);
    a3 += __shfl_down(a3, off, 64);
  }

  __shared__ float red[4][4];           // [wave][o]
  if (lane == 0) {
    red[wave][0] = a0;
    red[wave][1] = a1;
    red[wave][2] = a2;
    red[wave][3] = a3;
  }
  __syncthreads();

  if (tid < 4) {                        // thread o handles output o
    const int o = tid;
    const float s = red[0][o] + red[1][o] + red[2][o] + red[3][o];
    const float v = s / (float)cnt + b[o];
    out[seg * 4 + o] = 1.0f / (1.0f + expf(-v));
  }
}

// ---------------------------------------------------------------------------
extern "C" void kernel_launch(void* const* d_in, const int* in_sizes, int n_in,
                              void* d_out, int out_size, void* d_ws, size_t ws_size,
                              hipStream_t stream) {
  const float* x        = (const float*)d_in[0];
  const int*   node_num = (const int*)d_in[1];   // int32 on device (JAX default)
  const float* W        = (const float*)d_in[2];
  const float* b        = (const float*)d_in[3];
  float*       out      = (float*)d_out;

  const int B = in_sizes[1];                     // 4096 segments
  int* offsets = (int*)d_ws;                     // 16 KB scratch

  seg_offsets_kernel<<<1, BDIM, 0, stream>>>(node_num, offsets, B);
  mean_proj_kernel<<<B, BDIM, 0, stream>>>(x, node_num, offsets, W, b, out);
}